// Round 19
// baseline (404.083 us; speedup 1.0000x reference)
//
#include <hip/hip_runtime.h>
#include <hip/hip_bf16.h>

typedef unsigned int u32;
typedef unsigned short u16;
typedef __attribute__((ext_vector_type(8))) short bf16x8;
typedef __attribute__((ext_vector_type(4))) float f32x4;

// Problem constants
#define NWORDS 4096   // B*S
#define CC 32         // chars per word
#define EE 128        // embed dim
#define HHH 256       // hidden
#define MMW 32        // words per block (2 m-tiles per wave)
#define VOCABN 262

// LDS row stride for h arrays (fastest measured, R15/R18)
#define HS 264

// Workspace layout (u16 units):
//   HH pack per dir: frag[(nt*3+g)*8+kc][lane][8] -> 16*3*8*512 = 196608 u16 (bf16 hi of Whh)
//   XP table per dir: [262][768] bf16 = embed @ Wih^T (no bias)
//   bias: per dir 1024 f32: [0..511]=bih+bhh(r,z); [512..767]=bih_n; [768..1023]=bhh_n
#define PK_HHD (16*3*8*512)                  // 196608
#define XP_OFF_U16 (2*PK_HHD)                // 393216
#define XPD (VOCABN*768)                     // 201216
#define BIAS_OFF_U16 (XP_OFF_U16 + 2*XPD)    // 795648 (byte 1591296, 4-aligned)

// fused-prep grid split
#define XP_NCH 8
#define XP_CBLK ((VOCABN + XP_NCH - 1) / XP_NCH)      // 33
#define PREP_PACK_BLKS (2*PK_HHD/256)                 // 1536
#define PREP_XP_BLKS (XP_CBLK*2)                      // 66
#define PREP_BLKS (PREP_PACK_BLKS + PREP_XP_BLKS + 1) // 1603

__device__ __forceinline__ float bf2f(u16 u){ union{u32 i; float f;} v; v.i=((u32)u)<<16; return v.f; }
__device__ __forceinline__ u16 f2bf(float f){
  __hip_bfloat16 h = __float2bfloat16(f);   // rne
  u16 r; __builtin_memcpy(&r, &h, 2); return r;
}
__device__ __forceinline__ float sigmoid_f(float x){
  float e = __builtin_amdgcn_exp2f(-1.4426950408889634f * x);
  return __builtin_amdgcn_rcpf(1.0f + e);
}
__device__ __forceinline__ float tanh_f(float x){
  float ax = __builtin_fabsf(x);
  float e  = __builtin_amdgcn_exp2f(-2.8853900817779268f * ax);
  float t  = 1.0f - 2.0f * e * __builtin_amdgcn_rcpf(1.0f + e);
  return __builtin_copysignf(t, x);
}

// ---- fused prep: Whh pack + tiled XP table + biases, one launch (R15) ----
__global__ void prep_all(const float* __restrict__ emb,
                         const float* __restrict__ Wih_fw, const float* __restrict__ Whh_fw,
                         const float* __restrict__ bih_fw, const float* __restrict__ bhh_fw,
                         const float* __restrict__ Wih_bw, const float* __restrict__ Whh_bw,
                         const float* __restrict__ bih_bw, const float* __restrict__ bhh_bw,
                         u16* __restrict__ wsu)
{
  const int bid = blockIdx.x, tid = threadIdx.x;
  if (bid < PREP_PACK_BLKS) {
    // -------- Whh pack (bf16 hi only) --------
    int idx = bid*256 + tid;                  // 2*PK_HHD elements
    int d = idx / PK_HHD;
    int e = idx - d*PK_HHD;
    const float* Whh = d ? Whh_bw : Whh_fw;
    int jj   = e & 7;
    int lane = (e >> 3) & 63;
    int kc   = (e >> 9) & 7;
    int gnt  = e >> 12;                       // nt*3+g, < 48
    int g = gnt % 3, nt = gnt / 3;
    int row = g*256 + nt*16 + (lane & 15);
    int k   = kc*32 + ((lane >> 4) << 3) + jj;
    wsu[idx] = f2bf(Whh[row*HHH + k]);
  } else if (bid < PREP_PACK_BLKS + PREP_XP_BLKS) {
    // -------- XP table, tiled: block = (8 chars x dir), embed rows in LDS --------
    const int b    = bid - PREP_PACK_BLKS;
    const int dirb = b & 1;
    const int c0   = (b >> 1) * XP_NCH;
    const float* Wih = dirb ? Wih_bw : Wih_fw;
    u16* xpo = wsu + XP_OFF_U16 + (size_t)dirb*XPD;

    __shared__ float sh_E[XP_NCH][EE];        // 4 KB
    for (int i = tid; i < XP_NCH*EE; i += 256) {
      int c = c0 + i/EE;
      sh_E[0][i] = (c < VOCABN) ? emb[(size_t)c*EE + (i & (EE-1))] : 0.0f;
    }
    __syncthreads();

    #pragma unroll 1
    for (int q = 0; q < 3; ++q) {             // gate channel g = q*256 + tid
      const int g = q*256 + tid;
      const float* W = Wih + (size_t)g*EE;
      float acc[XP_NCH];
      #pragma unroll
      for (int c = 0; c < XP_NCH; ++c) acc[c] = 0.0f;
      #pragma unroll 2
      for (int k = 0; k < EE; k += 4) {
        float4 wv = *(const float4*)(W + k);
        #pragma unroll
        for (int c = 0; c < XP_NCH; ++c) {
          float4 ev = *(const float4*)(&sh_E[c][k]);
          acc[c] = fmaf(ev.w, wv.w, fmaf(ev.z, wv.z, fmaf(ev.y, wv.y, fmaf(ev.x, wv.x, acc[c]))));
        }
      }
      #pragma unroll
      for (int c = 0; c < XP_NCH; ++c) {
        int ci = c0 + c;
        if (ci < VOCABN) xpo[(size_t)ci*768 + g] = f2bf(acc[c]);
      }
    }
  } else {
    // -------- biases (one block handles all 2048, 8 per thread) --------
    #pragma unroll
    for (int rep = 0; rep < 8; ++rep) {
      int i = rep*256 + tid;
      int d = i >> 10, o = i & 1023;
      const float* bih = d ? bih_bw : bih_fw;
      const float* bhh = d ? bhh_bw : bhh_fw;
      float v;
      if (o < 512)      v = bih[o] + bhh[o];
      else if (o < 768) v = bih[o - 512 + 512];   // bih_n
      else              v = bhh[o - 768 + 512];   // bhh_n
      ((float*)(wsu + BIAS_OFF_U16))[d*1024 + o] = v;
    }
  }
}

// ==== R18 structure, sh_xp LDS round-trip replaced by per-lane register gather.
// Each lane needs exactly 24 xp scalars/step (3 gates x its 8 (word,ch) pairs)
// at addresses it can compute itself. Loads are issued right after S0 (same
// program point as the validated R15/R18 gather; same aggregate bytes), held
// in VGPRs across the MFMA phase, consumed in the epilogue. Removes the xp
// LDS stores/reads (bank conflicts + S2-drain weight) and 50 KB of LDS.
__global__ __launch_bounds__(1024)
void gru_mfma(const int* __restrict__ chars, const int* __restrict__ chars_mask,
              const int* __restrict__ data_mask, const u16* __restrict__ wsu,
              float* __restrict__ out)
{
  const int dir   = blockIdx.x & 1;           // XCD parity: one dir per XCD
  const int word0 = (blockIdx.x >> 1) * MMW;
  const int j     = threadIdx.x;              // 0..1023 = 16 waves (4 per SIMD)
  const int wave  = j >> 6, lane = j & 63;
  const int quad  = lane >> 4, l15 = lane & 15;

  const bf16x8* pHH  = (const bf16x8*)(wsu + (size_t)dir*PK_HHD);
  const u16*    xpt  = wsu + XP_OFF_U16 + (size_t)dir*XPD;
  const float*  bias = (const float*)(wsu + BIAS_OFF_U16) + dir*1024;

  // this wave owns gate-tile nt == wave (16 output channels)
  const bf16x8* bHH = pHH + (size_t)(wave*3)*8*64 + lane;

  __shared__ __align__(16) u16   sh_hhi[MMW][HS];     // bf16 hi of h, A-layout (16.9 KB)
  __shared__ __align__(16) u16   sh_hlo[MMW][HS];     // bf16 lo of h           (16.9 KB)
  __shared__ int   sh_ci[MMW][CC + 1];                // chars block            (4.2 KB)
  __shared__ float sh_cm[MMW][CC + 1];                // chars_mask block       (4.2 KB)

  // ---- one-time staging: chars/mask (1024 threads == MMW*CC), zero h ----
  {
    const int w = j >> 5, c = j & 31;
    sh_ci[w][c] = chars[(word0 + w)*CC + c];
    sh_cm[w][c] = (float)chars_mask[(word0 + w)*CC + c];
  }
  for (int i = j; i < MMW*HS/2; i += 1024) { ((float*)sh_hhi)[i] = 0.0f; ((float*)sh_hlo)[i] = 0.0f; }

  const int ch = wave*16 + l15;             // this lane's output channel
  const float bR  = bias[ch],        bZ  = bias[256 + ch];
  const float bXN = bias[512 + ch],  bHN = bias[768 + ch];

  // 8 HH batches per step (kc 0..7), 3 frags each. FOUR buffer slots so the
  // rotation is step-aligned (8 % 4 == 0; 3 slots permuted kc across steps).
  bf16x8 buf[4][3];
  auto load_batch = [&](int kc, bf16x8 dst[3]) {
    #pragma unroll
    for (int g = 0; g < 3; ++g) dst[g] = bHH[(g*8 + kc)*64];
  };
  load_batch(0, buf[0]);
  load_batch(1, buf[1]);
  load_batch(2, buf[2]);

  #pragma unroll 1
  for (int s = 0; s < CC; ++s) {
    const int t = dir ? (CC - 1 - s) : s;
    __syncthreads();                       // S0: h(s-1) writes visible to MFMA reads

    // ---- per-lane xp gather into registers (consumed after S2, in epilogue).
    // Within a quad, 16 lanes read 16 consecutive u16 -> 32B segments.
    u16 gxr[2][4], gxz[2][4], gxn[2][4];
    #pragma unroll
    for (int m = 0; m < 2; ++m)
      #pragma unroll
      for (int r = 0; r < 4; ++r) {
        const int word = m*16 + quad*4 + r;
        const u16* row = xpt + (size_t)sh_ci[word][t]*768 + ch;
        gxr[m][r] = row[0];
        gxz[m][r] = row[256];
        gxn[m][r] = row[512];
      }

    // acc[0]=r, acc[1]=z, acc[2]=hn ; [m-tile]  (24 regs)
    f32x4 acc[3][2];
    #pragma unroll
    for (int m = 0; m < 2; ++m) {
      acc[0][m] = (f32x4){bR,bR,bR,bR};
      acc[1][m] = (f32x4){bZ,bZ,bZ,bZ};
      acc[2][m] = (f32x4){bHN,bHN,bHN,bHN};
    }

    // r,z gates: h_hi only (bounded, non-compounding error). n gate: exact hi+lo.
    auto mfma_batch = [&](int kc, bf16x8 src[3]) {
      #pragma unroll
      for (int m = 0; m < 2; ++m) {
        bf16x8 ah = *(const bf16x8*)&sh_hhi[m*16 + l15][kc*32 + quad*8];
        bf16x8 al = *(const bf16x8*)&sh_hlo[m*16 + l15][kc*32 + quad*8];
        acc[0][m] = __builtin_amdgcn_mfma_f32_16x16x32_bf16(ah, src[0], acc[0][m], 0,0,0);
        acc[1][m] = __builtin_amdgcn_mfma_f32_16x16x32_bf16(ah, src[1], acc[1][m], 0,0,0);
        acc[2][m] = __builtin_amdgcn_mfma_f32_16x16x32_bf16(ah, src[2], acc[2][m], 0,0,0);
        acc[2][m] = __builtin_amdgcn_mfma_f32_16x16x32_bf16(al, src[2], acc[2][m], 0,0,0);
      }
    };

    #pragma unroll
    for (int b = 0; b < 8; ++b) {
      mfma_batch(b, buf[b & 3]);
      load_batch((b + 3) & 7, buf[(b + 3) & 3]);       // b>=5 pre-issues next step's 0,1,2
    }

    __syncthreads();                       // S2: all h fragment reads done

    // ---- gate math + h update (xp already in registers) ----
    #pragma unroll
    for (int m = 0; m < 2; ++m)
      #pragma unroll
      for (int r = 0; r < 4; ++r) {
        const int word = m*16 + quad*4 + r;
        float rr = sigmoid_f(acc[0][m][r] + bf2f(gxr[m][r]));
        float zz = sigmoid_f(acc[1][m][r] + bf2f(gxz[m][r]));
        float nn = tanh_f(fmaf(rr, acc[2][m][r], bXN + bf2f(gxn[m][r])));
        float hold = bf2f(sh_hhi[word][ch]) + bf2f(sh_hlo[word][ch]);
        float hnew = fmaf(zz, hold - nn, nn);                  // (1-z)*n + z*h
        float hm   = fmaf(sh_cm[word][t], hnew - hold, hold);  // mask freeze
        u16 hi = f2bf(hm);
        sh_hhi[word][ch] = hi;
        sh_hlo[word][ch] = f2bf(hm - bf2f(hi));
      }
  }
  __syncthreads();

  // ---- output: 32 words x 256 ch, coalesced fp32 ----
  const int oc = j & 255, og = j >> 8;     // 4 groups of 8 words
  #pragma unroll
  for (int i = 0; i < 8; ++i) {
    const int w = og*8 + i;
    float dm = (float)data_mask[word0 + w];
    float h = bf2f(sh_hhi[w][oc]) + bf2f(sh_hlo[w][oc]);
    out[(size_t)(word0 + w)*(2*HHH) + dir*HHH + oc] = h * dm;
  }
}

extern "C" void kernel_launch(void* const* d_in, const int* in_sizes, int n_in,
                              void* d_out, int out_size, void* d_ws, size_t ws_size,
                              hipStream_t stream) {
  const int*   chars      = (const int*)d_in[0];
  const int*   chars_mask = (const int*)d_in[1];
  const int*   data_mask  = (const int*)d_in[2];
  const float* embed      = (const float*)d_in[3];
  const float* Wih_fw     = (const float*)d_in[4];
  const float* Whh_fw     = (const float*)d_in[5];
  const float* bih_fw     = (const float*)d_in[6];
  const float* bhh_fw     = (const float*)d_in[7];
  const float* Wih_bw     = (const float*)d_in[8];
  const float* Whh_bw     = (const float*)d_in[9];
  const float* bih_bw     = (const float*)d_in[10];
  const float* bhh_bw     = (const float*)d_in[11];
  u16* wsu = (u16*)d_ws;

  prep_all<<<PREP_BLKS, 256, 0, stream>>>(embed, Wih_fw, Whh_fw, bih_fw, bhh_fw,
                                          Wih_bw, Whh_bw, bih_bw, bhh_bw, wsu);

  // 256 blocks: (word-group, dir) packed so dir == blockIdx&1 (XCD parity)
  gru_mfma<<<(NWORDS/MMW)*2, 1024, 0, stream>>>(chars, chars_mask, data_mask, wsu, (float*)d_out);
}

// Round 20
// 354.600 us; speedup vs baseline: 1.1395x; 1.1395x over previous
//
#include <hip/hip_runtime.h>
#include <hip/hip_bf16.h>

typedef unsigned int u32;
typedef unsigned short u16;
typedef __attribute__((ext_vector_type(8))) short bf16x8;
typedef __attribute__((ext_vector_type(4))) float f32x4;

// Problem constants
#define NWORDS 4096   // B*S
#define CC 32         // chars per word
#define EE 128        // embed dim
#define HHH 256       // hidden
#define MMW 32        // words per block (2 m-tiles per wave)
#define VOCABN 262

// LDS row strides
#define HS 264        // u16 stride for h arrays (fastest measured, R15/R18)
#define XPS 784       // u16 stride for xp rows (392 dw)

// Workspace layout (u16 units):
//   HH pack per dir: frag[(nt*3+g)*8+kc][lane][8] -> 16*3*8*512 = 196608 u16 (bf16 hi of Whh)
//   XP table per dir: [262][768] bf16 = embed @ Wih^T (no bias)
//   bias: per dir 1024 f32: [0..511]=bih+bhh(r,z); [512..767]=bih_n; [768..1023]=bhh_n
#define PK_HHD (16*3*8*512)                  // 196608
#define XP_OFF_U16 (2*PK_HHD)                // 393216
#define XPD (VOCABN*768)                     // 201216
#define BIAS_OFF_U16 (XP_OFF_U16 + 2*XPD)    // 795648 (byte 1591296, 4-aligned)

// fused-prep grid split
#define XP_NCH 8
#define XP_CBLK ((VOCABN + XP_NCH - 1) / XP_NCH)      // 33
#define PREP_PACK_BLKS (2*PK_HHD/256)                 // 1536
#define PREP_XP_BLKS (XP_CBLK*2)                      // 66
#define PREP_BLKS (PREP_PACK_BLKS + PREP_XP_BLKS + 1) // 1603

__device__ __forceinline__ float bf2f(u16 u){ union{u32 i; float f;} v; v.i=((u32)u)<<16; return v.f; }
__device__ __forceinline__ u16 f2bf(float f){
  __hip_bfloat16 h = __float2bfloat16(f);   // rne
  u16 r; __builtin_memcpy(&r, &h, 2); return r;
}
__device__ __forceinline__ float sigmoid_f(float x){
  float e = __builtin_amdgcn_exp2f(-1.4426950408889634f * x);
  return __builtin_amdgcn_rcpf(1.0f + e);
}
__device__ __forceinline__ float tanh_f(float x){
  float ax = __builtin_fabsf(x);
  float e  = __builtin_amdgcn_exp2f(-2.8853900817779268f * ax);
  float t  = 1.0f - 2.0f * e * __builtin_amdgcn_rcpf(1.0f + e);
  return __builtin_copysignf(t, x);
}

// ---- fused prep: Whh pack + tiled XP table + biases, one launch (R15) ----
__global__ void prep_all(const float* __restrict__ emb,
                         const float* __restrict__ Wih_fw, const float* __restrict__ Whh_fw,
                         const float* __restrict__ bih_fw, const float* __restrict__ bhh_fw,
                         const float* __restrict__ Wih_bw, const float* __restrict__ Whh_bw,
                         const float* __restrict__ bih_bw, const float* __restrict__ bhh_bw,
                         u16* __restrict__ wsu)
{
  const int bid = blockIdx.x, tid = threadIdx.x;
  if (bid < PREP_PACK_BLKS) {
    // -------- Whh pack (bf16 hi only) --------
    int idx = bid*256 + tid;                  // 2*PK_HHD elements
    int d = idx / PK_HHD;
    int e = idx - d*PK_HHD;
    const float* Whh = d ? Whh_bw : Whh_fw;
    int jj   = e & 7;
    int lane = (e >> 3) & 63;
    int kc   = (e >> 9) & 7;
    int gnt  = e >> 12;                       // nt*3+g, < 48
    int g = gnt % 3, nt = gnt / 3;
    int row = g*256 + nt*16 + (lane & 15);
    int k   = kc*32 + ((lane >> 4) << 3) + jj;
    wsu[idx] = f2bf(Whh[row*HHH + k]);
  } else if (bid < PREP_PACK_BLKS + PREP_XP_BLKS) {
    // -------- XP table, tiled: block = (8 chars x dir), embed rows in LDS --------
    const int b    = bid - PREP_PACK_BLKS;
    const int dirb = b & 1;
    const int c0   = (b >> 1) * XP_NCH;
    const float* Wih = dirb ? Wih_bw : Wih_fw;
    u16* xpo = wsu + XP_OFF_U16 + (size_t)dirb*XPD;

    __shared__ float sh_E[XP_NCH][EE];        // 4 KB
    for (int i = tid; i < XP_NCH*EE; i += 256) {
      int c = c0 + i/EE;
      sh_E[0][i] = (c < VOCABN) ? emb[(size_t)c*EE + (i & (EE-1))] : 0.0f;
    }
    __syncthreads();

    #pragma unroll 1
    for (int q = 0; q < 3; ++q) {             // gate channel g = q*256 + tid
      const int g = q*256 + tid;
      const float* W = Wih + (size_t)g*EE;
      float acc[XP_NCH];
      #pragma unroll
      for (int c = 0; c < XP_NCH; ++c) acc[c] = 0.0f;
      #pragma unroll 2
      for (int k = 0; k < EE; k += 4) {
        float4 wv = *(const float4*)(W + k);
        #pragma unroll
        for (int c = 0; c < XP_NCH; ++c) {
          float4 ev = *(const float4*)(&sh_E[c][k]);
          acc[c] = fmaf(ev.w, wv.w, fmaf(ev.z, wv.z, fmaf(ev.y, wv.y, fmaf(ev.x, wv.x, acc[c]))));
        }
      }
      #pragma unroll
      for (int c = 0; c < XP_NCH; ++c) {
        int ci = c0 + c;
        if (ci < VOCABN) xpo[(size_t)ci*768 + g] = f2bf(acc[c]);
      }
    }
  } else {
    // -------- biases (one block handles all 2048, 8 per thread) --------
    #pragma unroll
    for (int rep = 0; rep < 8; ++rep) {
      int i = rep*256 + tid;
      int d = i >> 10, o = i & 1023;
      const float* bih = d ? bih_bw : bih_fw;
      const float* bhh = d ? bhh_bw : bhh_fw;
      float v;
      if (o < 512)      v = bih[o] + bhh[o];
      else if (o < 768) v = bih[o - 512 + 512];   // bih_n
      else              v = bhh[o - 768 + 512];   // bhh_n
      ((float*)(wsu + BIAS_OFF_U16))[d*1024 + o] = v;
    }
  }
}

// ==== R18 measured-best gru kernel (291.5 us dispatch), restored verbatim.
// 2 barriers/step: sh_xp written in staging, read only in epilogue (after S2);
// MFMA phase never touches it. Cooperative uint4 gather -> LDS beats per-lane
// scalar gather (R19: fewer bytes/conflicts but worse time -- issue-rate and
// vmcnt-drain shape dominate).
__global__ __launch_bounds__(1024)
void gru_mfma(const int* __restrict__ chars, const int* __restrict__ chars_mask,
              const int* __restrict__ data_mask, const u16* __restrict__ wsu,
              float* __restrict__ out)
{
  const int dir   = blockIdx.x & 1;           // XCD parity: one dir per XCD
  const int word0 = (blockIdx.x >> 1) * MMW;
  const int j     = threadIdx.x;              // 0..1023 = 16 waves (4 per SIMD)
  const int wave  = j >> 6, lane = j & 63;
  const int quad  = lane >> 4, l15 = lane & 15;

  const bf16x8* pHH  = (const bf16x8*)(wsu + (size_t)dir*PK_HHD);
  const u16*    xpt  = wsu + XP_OFF_U16 + (size_t)dir*XPD;
  const float*  bias = (const float*)(wsu + BIAS_OFF_U16) + dir*1024;

  // this wave owns gate-tile nt == wave (16 output channels)
  const bf16x8* bHH = pHH + (size_t)(wave*3)*8*64 + lane;

  __shared__ __align__(16) u16   sh_hhi[MMW][HS];     // bf16 hi of h, A-layout (16.9 KB)
  __shared__ __align__(16) u16   sh_hlo[MMW][HS];     // bf16 lo of h           (16.9 KB)
  __shared__ __align__(16) u16   sh_xp[MMW][XPS];     // xp rows (768 used)     (50.2 KB)
  __shared__ int   sh_ci[MMW][CC + 1];                // chars block            (4.2 KB)
  __shared__ float sh_cm[MMW][CC + 1];                // chars_mask block       (4.2 KB)

  // ---- one-time staging: chars/mask (1024 threads == MMW*CC), zero h ----
  {
    const int w = j >> 5, c = j & 31;
    sh_ci[w][c] = chars[(word0 + w)*CC + c];
    sh_cm[w][c] = (float)chars_mask[(word0 + w)*CC + c];
  }
  for (int i = j; i < MMW*HS/2; i += 1024) { ((float*)sh_hhi)[i] = 0.0f; ((float*)sh_hlo)[i] = 0.0f; }

  const int ch = wave*16 + l15;             // this lane's output channel
  const float bR  = bias[ch],        bZ  = bias[256 + ch];
  const float bXN = bias[512 + ch],  bHN = bias[768 + ch];

  const int sw = j >> 5, sp = j & 31;       // xp-staging: word (32), 24-u16 part (32)

  // 8 HH batches per step (kc 0..7), 3 frags each. FOUR buffer slots so the
  // rotation is step-aligned (8 % 4 == 0; 3 slots permuted kc across steps).
  bf16x8 buf[4][3];
  auto load_batch = [&](int kc, bf16x8 dst[3]) {
    #pragma unroll
    for (int g = 0; g < 3; ++g) dst[g] = bHH[(g*8 + kc)*64];
  };
  load_batch(0, buf[0]);
  load_batch(1, buf[1]);
  load_batch(2, buf[2]);

  #pragma unroll 1
  for (int s = 0; s < CC; ++s) {
    const int t = dir ? (CC - 1 - s) : s;
    __syncthreads();                                   // S0: h writes visible, prev xp reads done
    {
      int ci = sh_ci[sw][t];
      const uint4* src = (const uint4*)(xpt + (size_t)ci*768);   // 96 uint4 per row
      uint4 a0 = src[sp*3], a1 = src[sp*3+1], a2 = src[sp*3+2];
      *(uint4*)&sh_xp[sw][sp*24]      = a0;
      *(uint4*)&sh_xp[sw][sp*24 + 8]  = a1;
      *(uint4*)&sh_xp[sw][sp*24 + 16] = a2;
    }
    // (no S1: MFMA phase does not read sh_xp; S2 orders xp writes -> epilogue)

    // acc[0]=r, acc[1]=z, acc[2]=hn ; [m-tile]  (24 regs)
    f32x4 acc[3][2];
    #pragma unroll
    for (int m = 0; m < 2; ++m) {
      acc[0][m] = (f32x4){bR,bR,bR,bR};
      acc[1][m] = (f32x4){bZ,bZ,bZ,bZ};
      acc[2][m] = (f32x4){bHN,bHN,bHN,bHN};
    }

    // r,z gates: h_hi only (bounded, non-compounding error). n gate: exact hi+lo.
    auto mfma_batch = [&](int kc, bf16x8 src[3]) {
      #pragma unroll
      for (int m = 0; m < 2; ++m) {
        bf16x8 ah = *(const bf16x8*)&sh_hhi[m*16 + l15][kc*32 + quad*8];
        bf16x8 al = *(const bf16x8*)&sh_hlo[m*16 + l15][kc*32 + quad*8];
        acc[0][m] = __builtin_amdgcn_mfma_f32_16x16x32_bf16(ah, src[0], acc[0][m], 0,0,0);
        acc[1][m] = __builtin_amdgcn_mfma_f32_16x16x32_bf16(ah, src[1], acc[1][m], 0,0,0);
        acc[2][m] = __builtin_amdgcn_mfma_f32_16x16x32_bf16(ah, src[2], acc[2][m], 0,0,0);
        acc[2][m] = __builtin_amdgcn_mfma_f32_16x16x32_bf16(al, src[2], acc[2][m], 0,0,0);
      }
    };

    #pragma unroll
    for (int b = 0; b < 8; ++b) {
      mfma_batch(b, buf[b & 3]);
      load_batch((b + 3) & 7, buf[(b + 3) & 3]);       // b>=5 pre-issues next step's 0,1,2
    }

    __syncthreads();                                   // S2: h frag reads + xp writes done

    // ---- gate math + h update (lane owns (word, ch) pairs) ----
    #pragma unroll
    for (int m = 0; m < 2; ++m)
      #pragma unroll
      for (int r = 0; r < 4; ++r) {
        const int word = m*16 + quad*4 + r;
        float xr = bf2f(sh_xp[word][ch]);
        float xz = bf2f(sh_xp[word][256 + ch]);
        float xn = bf2f(sh_xp[word][512 + ch]);
        float rr = sigmoid_f(acc[0][m][r] + xr);
        float zz = sigmoid_f(acc[1][m][r] + xz);
        float nn = tanh_f(fmaf(rr, acc[2][m][r], bXN + xn));
        float hold = bf2f(sh_hhi[word][ch]) + bf2f(sh_hlo[word][ch]);
        float hnew = fmaf(zz, hold - nn, nn);                  // (1-z)*n + z*h
        float hm   = fmaf(sh_cm[word][t], hnew - hold, hold);  // mask freeze
        u16 hi = f2bf(hm);
        sh_hhi[word][ch] = hi;
        sh_hlo[word][ch] = f2bf(hm - bf2f(hi));
      }
  }
  __syncthreads();

  // ---- output: 32 words x 256 ch, coalesced fp32 ----
  const int oc = j & 255, og = j >> 8;     // 4 groups of 8 words
  #pragma unroll
  for (int i = 0; i < 8; ++i) {
    const int w = og*8 + i;
    float dm = (float)data_mask[word0 + w];
    float h = bf2f(sh_hhi[w][oc]) + bf2f(sh_hlo[w][oc]);
    out[(size_t)(word0 + w)*(2*HHH) + dir*HHH + oc] = h * dm;
  }
}

extern "C" void kernel_launch(void* const* d_in, const int* in_sizes, int n_in,
                              void* d_out, int out_size, void* d_ws, size_t ws_size,
                              hipStream_t stream) {
  const int*   chars      = (const int*)d_in[0];
  const int*   chars_mask = (const int*)d_in[1];
  const int*   data_mask  = (const int*)d_in[2];
  const float* embed      = (const float*)d_in[3];
  const float* Wih_fw     = (const float*)d_in[4];
  const float* Whh_fw     = (const float*)d_in[5];
  const float* bih_fw     = (const float*)d_in[6];
  const float* bhh_fw     = (const float*)d_in[7];
  const float* Wih_bw     = (const float*)d_in[8];
  const float* Whh_bw     = (const float*)d_in[9];
  const float* bih_bw     = (const float*)d_in[10];
  const float* bhh_bw     = (const float*)d_in[11];
  u16* wsu = (u16*)d_ws;

  prep_all<<<PREP_BLKS, 256, 0, stream>>>(embed, Wih_fw, Whh_fw, bih_fw, bhh_fw,
                                          Wih_bw, Whh_bw, bih_bw, bhh_bw, wsu);

  // 256 blocks: (word-group, dir) packed so dir == blockIdx&1 (XCD parity)
  gru_mfma<<<(NWORDS/MMW)*2, 1024, 0, stream>>>(chars, chars_mask, data_mask, wsu, (float*)d_out);
}